// Round 24
// baseline (107.158 us; speedup 1.0000x reference)
//
#include <hip/hip_runtime.h>
#include <hip/hip_bf16.h>
#include <math.h>

#define Bsz 4
#define Slen 2048
#define Hdim 576
#define NH 9
#define NKV 3
#define HD 64

typedef __bf16 bf16_t;
typedef __bf16 bf16x8 __attribute__((ext_vector_type(8)));
typedef float f32x4 __attribute__((ext_vector_type(4)));
typedef float f32x16 __attribute__((ext_vector_type(16)));
typedef unsigned int u32;
typedef unsigned int u32x4 __attribute__((ext_vector_type(4)));

static __device__ __forceinline__ bf16x8 load_cvt8(const float* __restrict__ src){
  float4 f0 = *reinterpret_cast<const float4*>(src);
  float4 f1 = *reinterpret_cast<const float4*>(src + 4);
  bf16x8 v;
  v[0]=(bf16_t)f0.x; v[1]=(bf16_t)f0.y; v[2]=(bf16_t)f0.z; v[3]=(bf16_t)f0.w;
  v[4]=(bf16_t)f1.x; v[5]=(bf16_t)f1.y; v[6]=(bf16_t)f1.z; v[7]=(bf16_t)f1.w;
  return v;
}

// async global->LDS, 16B per lane
static __device__ __forceinline__ void gload16(const bf16_t* g, bf16_t* l){
  __builtin_amdgcn_global_load_lds((const __attribute__((address_space(1))) void*)g,
                                   (__attribute__((address_space(3))) void*)l, 16, 0, 0);
}

static __device__ __forceinline__ float xhalf_sum(float x){
  return x + __shfl_xor(x, 32, 64);
}

// ---------------- Setup: RoPE tables + precast X/W to bf16 (fused) ----------------
__global__ void setup_kernel(const float* __restrict__ X,
                             const float* __restrict__ Wq,
                             const float* __restrict__ Wk,
                             const float* __restrict__ Wv,
                             const float* __restrict__ Wo,
                             bf16_t* __restrict__ Xb,
                             bf16_t* __restrict__ Wb,
                             bf16_t* __restrict__ Wob,
                             float* __restrict__ cost,
                             float* __restrict__ sint)
{
  const int bid = blockIdx.x;
  if (bid < 256){
    int i = bid * 256 + threadIdx.x;
    int j = i & 31;
    int p = i >> 5;
    double invf = pow(100000.0, -(double)j / 32.0);
    double ang = (double)p * invf;
    cost[i] = (float)cos(ang);
    sint[i] = (float)sin(ang);
    return;
  }
  const int NX  = 8192 * 576 / 8;
  const int NWq = 576 * 576 / 8;
  const int NWk = 192 * 576 / 8;
  int i = (bid - 256) * 256 + threadIdx.x;
  const int total = NX + NWq + 2 * NWk + NWq;
  if (i >= total) return;
  const float* src; bf16_t* dst; int off;
  if (i < NX)                    { src = X;  dst = Xb;            off = i; }
  else if (i < NX + NWq)         { src = Wq; dst = Wb;            off = i - NX; }
  else if (i < NX + NWq + NWk)   { src = Wk; dst = Wb + 331776;   off = i - NX - NWq; }
  else if (i < NX + NWq + 2*NWk) { src = Wv; dst = Wb + 442368;   off = i - NX - NWq - NWk; }
  else                           { src = Wo; dst = Wob;           off = i - NX - NWq - 2*NWk; }
  *reinterpret_cast<bf16x8*>(dst + (size_t)off * 8) = load_cvt8(src + (size_t)off * 8);
}

// ---------------- QKV projection GEMM v3 + fused RoPE: BM=128, BN=128 (2 heads) ----------------
__launch_bounds__(256)
__global__ void qkv_gemm_kernel(const bf16_t* __restrict__ Xb,
                                const bf16_t* __restrict__ Wb,
                                const int* __restrict__ pos_ids,
                                const float* __restrict__ cost,
                                const float* __restrict__ sint,
                                float qscale,
                                bf16_t* __restrict__ qbuf,
                                bf16_t* __restrict__ kbuf,
                                bf16_t* __restrict__ vtbuf)
{
  __shared__ bf16_t Ald[2][128 * 64];
  __shared__ bf16_t Bld[2][128 * 64];
  const int t = threadIdx.x, l = t & 63, w = t >> 6;
  const int wm = w >> 1, wn = w & 1;
  const int lane16 = l & 15, grp = l >> 4;
  const int m0 = blockIdx.x * 128;
  const int p  = blockIdx.y;                  // 0..7, B rows p*128..p*128+127
  const int nrow0 = p * 128;

  const int sr = l >> 3;
  const int sc = ((l & 7) ^ sr) * 8;

  f32x4 acc[4][4];
  #pragma unroll
  for (int mi = 0; mi < 4; ++mi)
    #pragma unroll
    for (int nj = 0; nj < 4; ++nj)
      acc[mi][nj] = (f32x4){0.f, 0.f, 0.f, 0.f};

  auto STAGE = [&](int kt, int buf){
    const int k0 = kt * 64;
    #pragma unroll
    for (int u = 0; u < 4; ++u)
      gload16(Xb + (size_t)(m0 + w * 32 + u * 8 + sr) * Hdim + k0 + sc,
              &Ald[buf][(w * 32 + u * 8) * 64]);
    #pragma unroll
    for (int u = 0; u < 4; ++u){
      int br = nrow0 + w * 32 + u * 8 + sr;
      if (br > 959) br = 959;                 // clamp padding rows (p=7 upper half)
      gload16(Wb + (size_t)br * Hdim + k0 + sc,
              &Bld[buf][(w * 32 + u * 8) * 64]);
    }
  };

  STAGE(0, 0);
  asm volatile("s_waitcnt vmcnt(0)" ::: "memory");
  __syncthreads();

  const int sl7 = lane16 & 7;
  for (int kt = 0; kt < 9; ++kt){
    const int buf = kt & 1;
    if (kt + 1 < 9) STAGE(kt + 1, buf ^ 1);
    #pragma unroll
    for (int ks = 0; ks < 2; ++ks){
      bf16x8 a[4], bb[4];
      #pragma unroll
      for (int mi = 0; mi < 4; ++mi){
        int row = wm * 64 + mi * 16 + lane16;
        a[mi] = *reinterpret_cast<const bf16x8*>(&Ald[buf][row * 64 + (((ks * 4 + grp) ^ sl7) * 8)]);
      }
      #pragma unroll
      for (int nj = 0; nj < 4; ++nj){
        int row = wn * 64 + (nj & 1) * 32 + (nj >> 1) * 16 + lane16;
        bb[nj] = *reinterpret_cast<const bf16x8*>(&Bld[buf][row * 64 + (((ks * 4 + grp) ^ sl7) * 8)]);
      }
      #pragma unroll
      for (int mi = 0; mi < 4; ++mi)
        #pragma unroll
        for (int nj = 0; nj < 4; ++nj)
          acc[mi][nj] = __builtin_amdgcn_mfma_f32_16x16x32_bf16(a[mi], bb[nj], acc[mi][nj], 0, 0, 0);
    }
    if (kt + 1 < 9){
      asm volatile("s_waitcnt vmcnt(0)" ::: "memory");
      __syncthreads();
    }
  }

  const int h15 = p * 2 + wn;                 // 0..15; 15 = padding
  if (h15 < 15){
    #pragma unroll
    for (int mi = 0; mi < 4; ++mi){
      #pragma unroll
      for (int k = 0; k < 2; ++k){
        const int d = k * 16 + lane16;        // 0..31
        #pragma unroll
        for (int j2 = 0; j2 < 4; ++j2){
          int m = m0 + wm * 64 + mi * 16 + grp * 4 + j2;
          int b = m >> 11;
          int s = m & 2047;
          float x0 = acc[mi][2 * k][j2], x1 = acc[mi][2 * k + 1][j2];
          if (h15 < 12){                      // RoPE on q,k only
            int pos = pos_ids[b * Slen + s];
            float c = cost[pos * 32 + d], sn = sint[pos * 32 + d];
            float scale = (h15 < 9) ? qscale : 1.0f;
            float o0 = (x0 * c - x1 * sn) * scale;
            float o1 = (x1 * c + x0 * sn) * scale;
            x0 = o0; x1 = o1;
          }
          if (h15 < 9){
            bf16_t* dst = qbuf + (((size_t)b * NH + h15) * Slen + s) * HD;
            dst[d] = (bf16_t)x0; dst[d + 32] = (bf16_t)x1;
          } else if (h15 < 12){
            bf16_t* dst = kbuf + (((size_t)b * NKV + (h15 - 9)) * Slen + s) * HD;
            dst[d] = (bf16_t)x0; dst[d + 32] = (bf16_t)x1;
          } else {
            bf16_t* dst = vtbuf + ((size_t)b * NKV + (h15 - 12)) * HD * Slen + s;
            dst[(size_t)d * Slen] = (bf16_t)x0; dst[(size_t)(d + 32) * Slen] = (bf16_t)x1;
          }
        }
      }
    }
  }
}

// ---------------- Flash attention v14 (R22): split-K + fixed-base softmax + GQA XCD grouping ----------------
__launch_bounds__(128)
__global__ void flash_attn_kernel(const bf16_t* __restrict__ qbuf,
                                  const bf16_t* __restrict__ kbuf,
                                  const bf16_t* __restrict__ vtbuf,
                                  u32* __restrict__ part_O,
                                  float* __restrict__ part_l)
{
  __shared__ bf16_t Kld[2][32 * 64];
  __shared__ bf16_t Vld[2][64 * 32];
  const int t = threadIdx.x, l = t & 63, w = t >> 6;
  const int l32 = l & 31, hi = l >> 5;

  const int flat = blockIdx.x;
  const int xcd = flat & 7, j = flat >> 3;        // j 0..287
  const int g   = (xcd >> 1) * 3 + j % 3;         // (b,kvh) group 0..11
  const int idx = 2 * (j / 3) + (xcd & 1);        // 0..191 within group
  const int b   = g / 3, kvh = g % 3;
  const int qt  = 31 - idx / 6;
  const int rem = idx % 6;
  const int h   = kvh * 3 + (rem >> 1);
  const int seg = rem & 1;
  const int bh  = b * NH + h;
  const int t0 = seg * (qt + 1);
  const int t1 = t0 + qt + 1;

  const bf16_t* qp = qbuf + ((size_t)b * NH + h) * Slen * HD;
  const bf16_t* kp = kbuf + ((size_t)b * NKV + kvh) * Slen * HD;
  const bf16_t* vp = vtbuf + ((size_t)b * NKV + kvh) * HD * Slen;

  const int krow = l >> 3;
  const int ksc  = ((l & 7) ^ krow) * 8;
  const int vrow = l >> 2;
  const int vsc  = ((l & 3) ^ ((vrow >> 1) & 3)) * 8;

  auto STAGE = [&](int kt, int buf){
    const int k0 = kt * 32;
    #pragma unroll
    for (int u = 0; u < 2; ++u){
      int ub = w * 2 + u;
      gload16(kp + (size_t)(k0 + ub * 8 + krow) * HD + ksc, &Kld[buf][ub * 512]);
    }
    #pragma unroll
    for (int u = 0; u < 2; ++u){
      int ub = w * 2 + u;
      gload16(vp + (size_t)(ub * 16 + vrow) * Slen + k0 + vsc, &Vld[buf][ub * 512]);
    }
  };

  // Q fragments first: drained implicitly by the first waitK
  const int q0 = qt * 64 + w * 32;
  bf16x8 aq[4];
  #pragma unroll
  for (int ds = 0; ds < 4; ++ds)
    aq[ds] = *reinterpret_cast<const bf16x8*>(qp + (size_t)(q0 + l32) * HD + ds * 16 + hi * 8);

  STAGE(t0, 0);
  if (t0 + 1 < t1) STAGE(t0 + 1, 1);

  f32x16 acco[2];   // O^T[d = db*32 + crow(r,hi)][q = l32], unnormalized (m = 0)
  #pragma unroll
  for (int db = 0; db < 2; ++db)
    #pragma unroll
    for (int r = 0; r < 16; ++r) acco[db][r] = 0.f;
  float lhalf = 0.f;                 // per-half row-sum partial; combined once at epilogue

  const int dt = 2 * qt + w;
  for (int kb = t0; kb < t1; ++kb){
    const int cur = (kb - t0) & 1;
    const bool rem1 = (kb + 1 < t1), rem2 = (kb + 2 < t1);

    // K(kb) ready: V(kb)(2) + stage(kb+1)(4) may remain
    if (rem1) asm volatile("s_waitcnt vmcnt(6)" ::: "memory");
    else      asm volatile("s_waitcnt vmcnt(2)" ::: "memory");
    __syncthreads();

    u32x4 pa0, pa1;
    if (kb <= dt){
      // ---- QK^T swapped ----
      f32x16 sacc;
      #pragma unroll
      for (int r = 0; r < 16; ++r) sacc[r] = 0.f;
      __builtin_amdgcn_s_setprio(1);
      #pragma unroll
      for (int ds = 0; ds < 4; ++ds){
        bf16x8 ak = *reinterpret_cast<const bf16x8*>(
            &Kld[cur][l32 * 64 + (((ds * 2 + hi) ^ (l32 & 7)) * 8)]);
        sacc = __builtin_amdgcn_mfma_f32_32x32x16_bf16(ak, aq[ds], sacc, 0, 0, 0);
      }
      __builtin_amdgcn_s_setprio(0);

      // ---- causal mask (diagonal tile only) ----
      if (kb == dt){
        #pragma unroll
        for (int r = 0; r < 16; ++r){
          int crow = (r & 3) + 8 * (r >> 2) + 4 * hi;
          if (crow > l32) sacc[r] = -1e30f;
        }
      }

      // ---- exp2 (fixed m = 0) + tree row sum into per-half partial ----
      #pragma unroll
      for (int r = 0; r < 16; ++r)
        sacc[r] = __builtin_amdgcn_exp2f(sacc[r]);
      float s0 = sacc[0] + sacc[1],  s1 = sacc[2] + sacc[3];
      float s2 = sacc[4] + sacc[5],  s3 = sacc[6] + sacc[7];
      float s4 = sacc[8] + sacc[9],  s5 = sacc[10] + sacc[11];
      float s6 = sacc[12] + sacc[13], s7 = sacc[14] + sacc[15];
      s0 += s1; s2 += s3; s4 += s5; s6 += s7;
      lhalf += (s0 + s2) + (s4 + s6);

      // ---- P -> bf16 B-fragments in-register ----
      u32 wv[8];
      #pragma unroll
      for (int jj = 0; jj < 8; ++jj){
        float lo = sacc[2 * jj], hp = sacc[2 * jj + 1];
        asm("v_cvt_pk_bf16_f32 %0, %1, %2" : "=v"(wv[jj]) : "v"(lo), "v"(hp));
      }
      asm volatile("v_permlane32_swap_b32 %0, %1" : "+v"(wv[0]), "+v"(wv[2]));
      asm volatile("v_permlane32_swap_b32 %0, %1" : "+v"(wv[1]), "+v"(wv[3]));
      asm volatile("v_permlane32_swap_b32 %0, %1" : "+v"(wv[4]), "+v"(wv[6]));
      asm volatile("v_permlane32_swap_b32 %0, %1" : "+v"(wv[5]), "+v"(wv[7]));
      pa0 = (u32x4){wv[0], wv[1], wv[2], wv[3]};
      pa1 = (u32x4){wv[4], wv[5], wv[6], wv[7]};
    }

    // V(kb) ready: stage(kb+1)(4) may remain
    if (rem1) asm volatile("s_waitcnt vmcnt(4)" ::: "memory");
    else      asm volatile("s_waitcnt vmcnt(0)" ::: "memory");
    __syncthreads();

    if (kb <= dt){
      // ---- PV swapped ----
      __builtin_amdgcn_s_setprio(1);
      #pragma unroll
      for (int ks = 0; ks < 2; ++ks){
        #pragma unroll
        for (int db = 0; db < 2; ++db){
          bf16x8 av = *reinterpret_cast<const bf16x8*>(
              &Vld[cur][(db * 32 + l32) * 32 + (((ks * 2 + hi) ^ ((l32 >> 1) & 3)) * 8)]);
          acco[db] = __builtin_amdgcn_mfma_f32_32x32x16_bf16(
              av, __builtin_bit_cast(bf16x8, ks ? pa1 : pa0), acco[db], 0, 0, 0);
        }
      }
      __builtin_amdgcn_s_setprio(0);
    }

    if (rem2){
      __syncthreads();            // all waves done reading buf(kb) before overwrite
      STAGE(kb + 2, cur);
    }
  }

  const float lrun = xhalf_sum(lhalf);

  // ---- partial epilogue: packed bf16 O^T pairs [d/2][q], fp32 l (m always 0) ----
  const int slot = (bh * 32 + qt) * 2 + seg;
  u32* po = part_O + ((size_t)slot * 2 + w) * 1024;
  float* pl = part_l + ((size_t)slot * 2 + w) * 64;
  #pragma unroll
  for (int db = 0; db < 2; ++db){
    #pragma unroll
    for (int jj = 0; jj < 8; ++jj){
      int r = 2 * jj;
      int d = db * 32 + (r & 3) + 8 * (r >> 2) + 4 * hi;   // even
      u32 pw;
      float lo = acco[db][r], hp = acco[db][r + 1];
      asm("v_cvt_pk_bf16_f32 %0, %1, %2" : "=v"(pw) : "v"(lo), "v"(hp));
      po[(d >> 1) * 32 + l32] = pw;
    }
  }
  if (hi == 0) pl[l32] = lrun;
}

// ---------------- Combine: merge 2 segments per q-row (all qt); m == 0 always ----------------
__launch_bounds__(128)
__global__ void combine_kernel(const u32* __restrict__ part_O,
                               const float* __restrict__ part_l,
                               bf16_t* __restrict__ attn_out)
{
  const int idx = blockIdx.x;           // 0..1151
  const int bh = idx % 36, qt = idx / 36;
  const int b = bh / NH, h = bh % NH;
  const int t = threadIdx.x;
  const int q = t & 31, wg = (t >> 5) & 1, half = t >> 6;
  const int slot0 = (bh * 32 + qt) * 2;

  const float* pl0 = part_l + ((size_t)(slot0 + 0) * 2 + wg) * 64;
  const float* pl1 = part_l + ((size_t)(slot0 + 1) * 2 + wg) * 64;
  float linv = 1.0f / (pl0[q] + pl1[q]);

  const u32* po0 = part_O + ((size_t)(slot0 + 0) * 2 + wg) * 1024;
  const u32* po1 = part_O + ((size_t)(slot0 + 1) * 2 + wg) * 1024;
  const int s = qt * 64 + wg * 32 + q;
  bf16_t* orow = attn_out + ((size_t)b * Slen + s) * (NH * HD) + h * HD;

  #pragma unroll
  for (int u = 0; u < 16; ++u){
    int dp = half * 16 + u;
    u32 v1 = po0[dp * 32 + q], v2 = po1[dp * 32 + q];
    float lo = (__builtin_bit_cast(float, v1 << 16)
              + __builtin_bit_cast(float, v2 << 16)) * linv;
    float hv = (__builtin_bit_cast(float, v1 & 0xffff0000u)
              + __builtin_bit_cast(float, v2 & 0xffff0000u)) * linv;
    u32 pw;
    asm("v_cvt_pk_bf16_f32 %0, %1, %2" : "=v"(pw) : "v"(lo), "v"(hv));
    *reinterpret_cast<u32*>(orow + 2 * dp) = pw;
  }
}

// ---------------- Output GEMM v3: BM=128, BN=128, grid (64,5); last n-tile is half ----------------
// Same lever as qkv v3: A (ab, 9.4MB) re-staged 5x instead of 9x; 32 MFMA per 32KB staged.
// nt=4 covers cols 512..575 only: B rows clamped to 575 (garbage confined to padding
// accumulators, never stored); epilogue writes only n < 576 (per-fragment uniform guard).
__launch_bounds__(256)
__global__ void out_gemm_kernel(const bf16_t* __restrict__ A,
                                const bf16_t* __restrict__ Wob,
                                float* __restrict__ out)
{
  __shared__ bf16_t Ald[2][128 * 64];
  __shared__ bf16_t Bld[2][128 * 64];
  const int t = threadIdx.x, l = t & 63, w = t >> 6;
  const int wm = w >> 1, wn = w & 1;
  const int lane16 = l & 15, grp = l >> 4;
  const int m0 = blockIdx.x * 128;
  const int nt = blockIdx.y;          // 0..4; nt==4 -> half tile
  const int nrow0 = nt * 128;

  const int sr = l >> 3;
  const int sc = ((l & 7) ^ sr) * 8;

  f32x4 acc[4][4];
  #pragma unroll
  for (int mi = 0; mi < 4; ++mi)
    #pragma unroll
    for (int nj = 0; nj < 4; ++nj)
      acc[mi][nj] = (f32x4){0.f, 0.f, 0.f, 0.f};

  auto STAGE = [&](int kt, int buf){
    const int k0 = kt * 64;
    #pragma unroll
    for (int u = 0; u < 4; ++u)
      gload16(A + (size_t)(m0 + w * 32 + u * 8 + sr) * Hdim + k0 + sc,
              &Ald[buf][(w * 32 + u * 8) * 64]);
    #pragma unroll
    for (int u = 0; u < 4; ++u){
      int br = nrow0 + w * 32 + u * 8 + sr;
      if (br > 575) br = 575;           // clamp padding rows (nt=4 upper half)
      gload16(Wob + (size_t)br * Hdim + k0 + sc,
              &Bld[buf][(w * 32 + u * 8) * 64]);
    }
  };

  STAGE(0, 0);
  asm volatile("s_waitcnt vmcnt(0)" ::: "memory");
  __syncthreads();

  const int sl7 = lane16 & 7;
  for (int kt = 0; kt < 9; ++kt){
    const int buf = kt & 1;
    if (kt + 1 < 9) STAGE(kt + 1, buf ^ 1);
    #pragma unroll
    for (int ks = 0; ks < 2; ++ks){
      bf16x8 a[4], bb[4];
      #pragma unroll
      for (int mi = 0; mi < 4; ++mi){
        int row = wm * 64 + mi * 16 + lane16;
        a[mi] = *reinterpret_cast<const bf16x8*>(&Ald[buf][row * 64 + (((ks * 4 + grp) ^ sl7) * 8)]);
      }
      #pragma unroll
      for (int nj = 0; nj < 4; ++nj){
        int row = wn * 64 + nj * 16 + lane16;
        bb[nj] = *reinterpret_cast<const bf16x8*>(&Bld[buf][row * 64 + (((ks * 4 + grp) ^ sl7) * 8)]);
      }
      #pragma unroll
      for (int mi = 0; mi < 4; ++mi)
        #pragma unroll
        for (int nj = 0; nj < 4; ++nj)
          acc[mi][nj] = __builtin_amdgcn_mfma_f32_16x16x32_bf16(a[mi], bb[nj], acc[mi][nj], 0, 0, 0);
    }
    if (kt + 1 < 9){
      asm volatile("s_waitcnt vmcnt(0)" ::: "memory");
      __syncthreads();
    }
  }

  #pragma unroll
  for (int mi = 0; mi < 4; ++mi){
    #pragma unroll
    for (int nj = 0; nj < 4; ++nj){
      const int nbase = nrow0 + wn * 64 + nj * 16;
      if (nbase < 576){                 // skip padding fragments (nt=4 upper half)
        #pragma unroll
        for (int jj = 0; jj < 4; ++jj){
          int m = m0 + wm * 64 + mi * 16 + grp * 4 + jj;
          int n = nbase + lane16;
          out[(size_t)m * Hdim + n] = acc[mi][nj][jj];
        }
      }
    }
  }
}

extern "C" void kernel_launch(void* const* d_in, const int* in_sizes, int n_in,
                              void* d_out, int out_size, void* d_ws, size_t ws_size,
                              hipStream_t stream) {
  const float* X   = (const float*)d_in[0];
  const int* pos   = (const int*)d_in[2];
  const float* Wq  = (const float*)d_in[3];
  const float* Wk  = (const float*)d_in[4];
  const float* Wv  = (const float*)d_in[5];
  const float* Wo  = (const float*)d_in[6];
  float* out = (float*)d_out;

  char* ws = (char*)d_ws;
  float* cost = (float*)ws;
  float* sint = (float*)(ws + 262144);
  bf16_t* qb  = (bf16_t*)(ws + 524288);
  bf16_t* kb  = qb + (size_t)Bsz * NH * Slen * HD;
  bf16_t* vt  = kb + (size_t)Bsz * NKV * Slen * HD;
  bf16_t* Xb  = vt + (size_t)Bsz * NKV * Slen * HD;
  bf16_t* ab  = Xb;                                  // alias: Xb dead after qkv_gemm
  bf16_t* Wb  = Xb + (size_t)8192 * 576;
  bf16_t* Wob = Wb + (size_t)960 * 576;
  u32*  part_O  = (u32*)(Wob + (size_t)576 * 576);   // 2304 slots x 2 waves x 4KB = 18.9MB
  float* part_l = (float*)(part_O + (size_t)2304 * 2 * 1024);  // 1.2MB

  const float QSCALE = 0.125f * 1.44269504088896f;

  setup_kernel<<<dim3(256 + 2736), dim3(256), 0, stream>>>(X, Wq, Wk, Wv, Wo, Xb, Wb, Wob, cost, sint);
  qkv_gemm_kernel<<<dim3(64, 8), dim3(256), 0, stream>>>(Xb, Wb, pos, cost, sint, QSCALE, qb, kb, vt);
  flash_attn_kernel<<<dim3(2304), dim3(128), 0, stream>>>(qb, kb, vt, part_O, part_l);
  combine_kernel<<<dim3(1152), dim3(128), 0, stream>>>(part_O, part_l, ab);
  out_gemm_kernel<<<dim3(64, 5), dim3(256), 0, stream>>>(ab, Wob, out);
}

// Round 25
// 104.602 us; speedup vs baseline: 1.0244x; 1.0244x over previous
//
#include <hip/hip_runtime.h>
#include <hip/hip_bf16.h>
#include <math.h>

#define Bsz 4
#define Slen 2048
#define Hdim 576
#define NH 9
#define NKV 3
#define HD 64

typedef __bf16 bf16_t;
typedef __bf16 bf16x8 __attribute__((ext_vector_type(8)));
typedef float f32x4 __attribute__((ext_vector_type(4)));
typedef float f32x16 __attribute__((ext_vector_type(16)));
typedef unsigned int u32;
typedef unsigned int u32x4 __attribute__((ext_vector_type(4)));

static __device__ __forceinline__ bf16x8 load_cvt8(const float* __restrict__ src){
  float4 f0 = *reinterpret_cast<const float4*>(src);
  float4 f1 = *reinterpret_cast<const float4*>(src + 4);
  bf16x8 v;
  v[0]=(bf16_t)f0.x; v[1]=(bf16_t)f0.y; v[2]=(bf16_t)f0.z; v[3]=(bf16_t)f0.w;
  v[4]=(bf16_t)f1.x; v[5]=(bf16_t)f1.y; v[6]=(bf16_t)f1.z; v[7]=(bf16_t)f1.w;
  return v;
}

// async global->LDS, 16B per lane
static __device__ __forceinline__ void gload16(const bf16_t* g, bf16_t* l){
  __builtin_amdgcn_global_load_lds((const __attribute__((address_space(1))) void*)g,
                                   (__attribute__((address_space(3))) void*)l, 16, 0, 0);
}

static __device__ __forceinline__ float xhalf_sum(float x){
  return x + __shfl_xor(x, 32, 64);
}

// ---------------- Setup: RoPE tables + precast X/W to bf16 (fused) ----------------
__global__ void setup_kernel(const float* __restrict__ X,
                             const float* __restrict__ Wq,
                             const float* __restrict__ Wk,
                             const float* __restrict__ Wv,
                             const float* __restrict__ Wo,
                             bf16_t* __restrict__ Xb,
                             bf16_t* __restrict__ Wb,
                             bf16_t* __restrict__ Wob,
                             float* __restrict__ cost,
                             float* __restrict__ sint)
{
  const int bid = blockIdx.x;
  if (bid < 256){
    int i = bid * 256 + threadIdx.x;
    int j = i & 31;
    int p = i >> 5;
    double invf = pow(100000.0, -(double)j / 32.0);
    double ang = (double)p * invf;
    cost[i] = (float)cos(ang);
    sint[i] = (float)sin(ang);
    return;
  }
  const int NX  = 8192 * 576 / 8;
  const int NWq = 576 * 576 / 8;
  const int NWk = 192 * 576 / 8;
  int i = (bid - 256) * 256 + threadIdx.x;
  const int total = NX + NWq + 2 * NWk + NWq;
  if (i >= total) return;
  const float* src; bf16_t* dst; int off;
  if (i < NX)                    { src = X;  dst = Xb;            off = i; }
  else if (i < NX + NWq)         { src = Wq; dst = Wb;            off = i - NX; }
  else if (i < NX + NWq + NWk)   { src = Wk; dst = Wb + 331776;   off = i - NX - NWq; }
  else if (i < NX + NWq + 2*NWk) { src = Wv; dst = Wb + 442368;   off = i - NX - NWq - NWk; }
  else                           { src = Wo; dst = Wob;           off = i - NX - NWq - 2*NWk; }
  *reinterpret_cast<bf16x8*>(dst + (size_t)off * 8) = load_cvt8(src + (size_t)off * 8);
}

// ---------------- QKV projection GEMM v3 + fused RoPE: BM=128, BN=128 (2 heads) ----------------
__launch_bounds__(256)
__global__ void qkv_gemm_kernel(const bf16_t* __restrict__ Xb,
                                const bf16_t* __restrict__ Wb,
                                const int* __restrict__ pos_ids,
                                const float* __restrict__ cost,
                                const float* __restrict__ sint,
                                float qscale,
                                bf16_t* __restrict__ qbuf,
                                bf16_t* __restrict__ kbuf,
                                bf16_t* __restrict__ vtbuf)
{
  __shared__ bf16_t Ald[2][128 * 64];
  __shared__ bf16_t Bld[2][128 * 64];
  const int t = threadIdx.x, l = t & 63, w = t >> 6;
  const int wm = w >> 1, wn = w & 1;
  const int lane16 = l & 15, grp = l >> 4;
  const int m0 = blockIdx.x * 128;
  const int p  = blockIdx.y;                  // 0..7, B rows p*128..p*128+127
  const int nrow0 = p * 128;

  const int sr = l >> 3;
  const int sc = ((l & 7) ^ sr) * 8;

  f32x4 acc[4][4];
  #pragma unroll
  for (int mi = 0; mi < 4; ++mi)
    #pragma unroll
    for (int nj = 0; nj < 4; ++nj)
      acc[mi][nj] = (f32x4){0.f, 0.f, 0.f, 0.f};

  auto STAGE = [&](int kt, int buf){
    const int k0 = kt * 64;
    #pragma unroll
    for (int u = 0; u < 4; ++u)
      gload16(Xb + (size_t)(m0 + w * 32 + u * 8 + sr) * Hdim + k0 + sc,
              &Ald[buf][(w * 32 + u * 8) * 64]);
    #pragma unroll
    for (int u = 0; u < 4; ++u){
      int br = nrow0 + w * 32 + u * 8 + sr;
      if (br > 959) br = 959;                 // clamp padding rows (p=7 upper half)
      gload16(Wb + (size_t)br * Hdim + k0 + sc,
              &Bld[buf][(w * 32 + u * 8) * 64]);
    }
  };

  STAGE(0, 0);
  asm volatile("s_waitcnt vmcnt(0)" ::: "memory");
  __syncthreads();

  const int sl7 = lane16 & 7;
  for (int kt = 0; kt < 9; ++kt){
    const int buf = kt & 1;
    if (kt + 1 < 9) STAGE(kt + 1, buf ^ 1);
    #pragma unroll
    for (int ks = 0; ks < 2; ++ks){
      bf16x8 a[4], bb[4];
      #pragma unroll
      for (int mi = 0; mi < 4; ++mi){
        int row = wm * 64 + mi * 16 + lane16;
        a[mi] = *reinterpret_cast<const bf16x8*>(&Ald[buf][row * 64 + (((ks * 4 + grp) ^ sl7) * 8)]);
      }
      #pragma unroll
      for (int nj = 0; nj < 4; ++nj){
        int row = wn * 64 + (nj & 1) * 32 + (nj >> 1) * 16 + lane16;
        bb[nj] = *reinterpret_cast<const bf16x8*>(&Bld[buf][row * 64 + (((ks * 4 + grp) ^ sl7) * 8)]);
      }
      #pragma unroll
      for (int mi = 0; mi < 4; ++mi)
        #pragma unroll
        for (int nj = 0; nj < 4; ++nj)
          acc[mi][nj] = __builtin_amdgcn_mfma_f32_16x16x32_bf16(a[mi], bb[nj], acc[mi][nj], 0, 0, 0);
    }
    if (kt + 1 < 9){
      asm volatile("s_waitcnt vmcnt(0)" ::: "memory");
      __syncthreads();
    }
  }

  const int h15 = p * 2 + wn;                 // 0..15; 15 = padding
  if (h15 < 15){
    #pragma unroll
    for (int mi = 0; mi < 4; ++mi){
      #pragma unroll
      for (int k = 0; k < 2; ++k){
        const int d = k * 16 + lane16;        // 0..31
        #pragma unroll
        for (int j2 = 0; j2 < 4; ++j2){
          int m = m0 + wm * 64 + mi * 16 + grp * 4 + j2;
          int b = m >> 11;
          int s = m & 2047;
          float x0 = acc[mi][2 * k][j2], x1 = acc[mi][2 * k + 1][j2];
          if (h15 < 12){                      // RoPE on q,k only
            int pos = pos_ids[b * Slen + s];
            float c = cost[pos * 32 + d], sn = sint[pos * 32 + d];
            float scale = (h15 < 9) ? qscale : 1.0f;
            float o0 = (x0 * c - x1 * sn) * scale;
            float o1 = (x1 * c + x0 * sn) * scale;
            x0 = o0; x1 = o1;
          }
          if (h15 < 9){
            bf16_t* dst = qbuf + (((size_t)b * NH + h15) * Slen + s) * HD;
            dst[d] = (bf16_t)x0; dst[d + 32] = (bf16_t)x1;
          } else if (h15 < 12){
            bf16_t* dst = kbuf + (((size_t)b * NKV + (h15 - 9)) * Slen + s) * HD;
            dst[d] = (bf16_t)x0; dst[d + 32] = (bf16_t)x1;
          } else {
            bf16_t* dst = vtbuf + ((size_t)b * NKV + (h15 - 12)) * HD * Slen + s;
            dst[(size_t)d * Slen] = (bf16_t)x0; dst[(size_t)(d + 32) * Slen] = (bf16_t)x1;
          }
        }
      }
    }
  }
}

// ---------------- Flash attention v14 (R22): split-K + fixed-base softmax + GQA XCD grouping ----------------
__launch_bounds__(128)
__global__ void flash_attn_kernel(const bf16_t* __restrict__ qbuf,
                                  const bf16_t* __restrict__ kbuf,
                                  const bf16_t* __restrict__ vtbuf,
                                  u32* __restrict__ part_O,
                                  float* __restrict__ part_l)
{
  __shared__ bf16_t Kld[2][32 * 64];
  __shared__ bf16_t Vld[2][64 * 32];
  const int t = threadIdx.x, l = t & 63, w = t >> 6;
  const int l32 = l & 31, hi = l >> 5;

  const int flat = blockIdx.x;
  const int xcd = flat & 7, j = flat >> 3;        // j 0..287
  const int g   = (xcd >> 1) * 3 + j % 3;         // (b,kvh) group 0..11
  const int idx = 2 * (j / 3) + (xcd & 1);        // 0..191 within group
  const int b   = g / 3, kvh = g % 3;
  const int qt  = 31 - idx / 6;
  const int rem = idx % 6;
  const int h   = kvh * 3 + (rem >> 1);
  const int seg = rem & 1;
  const int bh  = b * NH + h;
  const int t0 = seg * (qt + 1);
  const int t1 = t0 + qt + 1;

  const bf16_t* qp = qbuf + ((size_t)b * NH + h) * Slen * HD;
  const bf16_t* kp = kbuf + ((size_t)b * NKV + kvh) * Slen * HD;
  const bf16_t* vp = vtbuf + ((size_t)b * NKV + kvh) * HD * Slen;

  const int krow = l >> 3;
  const int ksc  = ((l & 7) ^ krow) * 8;
  const int vrow = l >> 2;
  const int vsc  = ((l & 3) ^ ((vrow >> 1) & 3)) * 8;

  auto STAGE = [&](int kt, int buf){
    const int k0 = kt * 32;
    #pragma unroll
    for (int u = 0; u < 2; ++u){
      int ub = w * 2 + u;
      gload16(kp + (size_t)(k0 + ub * 8 + krow) * HD + ksc, &Kld[buf][ub * 512]);
    }
    #pragma unroll
    for (int u = 0; u < 2; ++u){
      int ub = w * 2 + u;
      gload16(vp + (size_t)(ub * 16 + vrow) * Slen + k0 + vsc, &Vld[buf][ub * 512]);
    }
  };

  // Q fragments first: drained implicitly by the first waitK
  const int q0 = qt * 64 + w * 32;
  bf16x8 aq[4];
  #pragma unroll
  for (int ds = 0; ds < 4; ++ds)
    aq[ds] = *reinterpret_cast<const bf16x8*>(qp + (size_t)(q0 + l32) * HD + ds * 16 + hi * 8);

  STAGE(t0, 0);
  if (t0 + 1 < t1) STAGE(t0 + 1, 1);

  f32x16 acco[2];   // O^T[d = db*32 + crow(r,hi)][q = l32], unnormalized (m = 0)
  #pragma unroll
  for (int db = 0; db < 2; ++db)
    #pragma unroll
    for (int r = 0; r < 16; ++r) acco[db][r] = 0.f;
  float lhalf = 0.f;                 // per-half row-sum partial; combined once at epilogue

  const int dt = 2 * qt + w;
  for (int kb = t0; kb < t1; ++kb){
    const int cur = (kb - t0) & 1;
    const bool rem1 = (kb + 1 < t1), rem2 = (kb + 2 < t1);

    // K(kb) ready: V(kb)(2) + stage(kb+1)(4) may remain
    if (rem1) asm volatile("s_waitcnt vmcnt(6)" ::: "memory");
    else      asm volatile("s_waitcnt vmcnt(2)" ::: "memory");
    __syncthreads();

    u32x4 pa0, pa1;
    if (kb <= dt){
      // ---- QK^T swapped ----
      f32x16 sacc;
      #pragma unroll
      for (int r = 0; r < 16; ++r) sacc[r] = 0.f;
      __builtin_amdgcn_s_setprio(1);
      #pragma unroll
      for (int ds = 0; ds < 4; ++ds){
        bf16x8 ak = *reinterpret_cast<const bf16x8*>(
            &Kld[cur][l32 * 64 + (((ds * 2 + hi) ^ (l32 & 7)) * 8)]);
        sacc = __builtin_amdgcn_mfma_f32_32x32x16_bf16(ak, aq[ds], sacc, 0, 0, 0);
      }
      __builtin_amdgcn_s_setprio(0);

      // ---- causal mask (diagonal tile only) ----
      if (kb == dt){
        #pragma unroll
        for (int r = 0; r < 16; ++r){
          int crow = (r & 3) + 8 * (r >> 2) + 4 * hi;
          if (crow > l32) sacc[r] = -1e30f;
        }
      }

      // ---- exp2 (fixed m = 0) + tree row sum into per-half partial ----
      #pragma unroll
      for (int r = 0; r < 16; ++r)
        sacc[r] = __builtin_amdgcn_exp2f(sacc[r]);
      float s0 = sacc[0] + sacc[1],  s1 = sacc[2] + sacc[3];
      float s2 = sacc[4] + sacc[5],  s3 = sacc[6] + sacc[7];
      float s4 = sacc[8] + sacc[9],  s5 = sacc[10] + sacc[11];
      float s6 = sacc[12] + sacc[13], s7 = sacc[14] + sacc[15];
      s0 += s1; s2 += s3; s4 += s5; s6 += s7;
      lhalf += (s0 + s2) + (s4 + s6);

      // ---- P -> bf16 B-fragments in-register ----
      u32 wv[8];
      #pragma unroll
      for (int jj = 0; jj < 8; ++jj){
        float lo = sacc[2 * jj], hp = sacc[2 * jj + 1];
        asm("v_cvt_pk_bf16_f32 %0, %1, %2" : "=v"(wv[jj]) : "v"(lo), "v"(hp));
      }
      asm volatile("v_permlane32_swap_b32 %0, %1" : "+v"(wv[0]), "+v"(wv[2]));
      asm volatile("v_permlane32_swap_b32 %0, %1" : "+v"(wv[1]), "+v"(wv[3]));
      asm volatile("v_permlane32_swap_b32 %0, %1" : "+v"(wv[4]), "+v"(wv[6]));
      asm volatile("v_permlane32_swap_b32 %0, %1" : "+v"(wv[5]), "+v"(wv[7]));
      pa0 = (u32x4){wv[0], wv[1], wv[2], wv[3]};
      pa1 = (u32x4){wv[4], wv[5], wv[6], wv[7]};
    }

    // V(kb) ready: stage(kb+1)(4) may remain
    if (rem1) asm volatile("s_waitcnt vmcnt(4)" ::: "memory");
    else      asm volatile("s_waitcnt vmcnt(0)" ::: "memory");
    __syncthreads();

    if (kb <= dt){
      // ---- PV swapped ----
      __builtin_amdgcn_s_setprio(1);
      #pragma unroll
      for (int ks = 0; ks < 2; ++ks){
        #pragma unroll
        for (int db = 0; db < 2; ++db){
          bf16x8 av = *reinterpret_cast<const bf16x8*>(
              &Vld[cur][(db * 32 + l32) * 32 + (((ks * 2 + hi) ^ ((l32 >> 1) & 3)) * 8)]);
          acco[db] = __builtin_amdgcn_mfma_f32_32x32x16_bf16(
              av, __builtin_bit_cast(bf16x8, ks ? pa1 : pa0), acco[db], 0, 0, 0);
        }
      }
      __builtin_amdgcn_s_setprio(0);
    }

    if (rem2){
      __syncthreads();            // all waves done reading buf(kb) before overwrite
      STAGE(kb + 2, cur);
    }
  }

  const float lrun = xhalf_sum(lhalf);

  // ---- partial epilogue: packed bf16 O^T pairs [d/2][q], fp32 l (m always 0) ----
  const int slot = (bh * 32 + qt) * 2 + seg;
  u32* po = part_O + ((size_t)slot * 2 + w) * 1024;
  float* pl = part_l + ((size_t)slot * 2 + w) * 64;
  #pragma unroll
  for (int db = 0; db < 2; ++db){
    #pragma unroll
    for (int jj = 0; jj < 8; ++jj){
      int r = 2 * jj;
      int d = db * 32 + (r & 3) + 8 * (r >> 2) + 4 * hi;   // even
      u32 pw;
      float lo = acco[db][r], hp = acco[db][r + 1];
      asm("v_cvt_pk_bf16_f32 %0, %1, %2" : "=v"(pw) : "v"(lo), "v"(hp));
      po[(d >> 1) * 32 + l32] = pw;
    }
  }
  if (hi == 0) pl[l32] = lrun;
}

// ---------------- Combine: merge 2 segments per q-row (all qt); m == 0 always ----------------
__launch_bounds__(128)
__global__ void combine_kernel(const u32* __restrict__ part_O,
                               const float* __restrict__ part_l,
                               bf16_t* __restrict__ attn_out)
{
  const int idx = blockIdx.x;           // 0..1151
  const int bh = idx % 36, qt = idx / 36;
  const int b = bh / NH, h = bh % NH;
  const int t = threadIdx.x;
  const int q = t & 31, wg = (t >> 5) & 1, half = t >> 6;
  const int slot0 = (bh * 32 + qt) * 2;

  const float* pl0 = part_l + ((size_t)(slot0 + 0) * 2 + wg) * 64;
  const float* pl1 = part_l + ((size_t)(slot0 + 1) * 2 + wg) * 64;
  float linv = 1.0f / (pl0[q] + pl1[q]);

  const u32* po0 = part_O + ((size_t)(slot0 + 0) * 2 + wg) * 1024;
  const u32* po1 = part_O + ((size_t)(slot0 + 1) * 2 + wg) * 1024;
  const int s = qt * 64 + wg * 32 + q;
  bf16_t* orow = attn_out + ((size_t)b * Slen + s) * (NH * HD) + h * HD;

  #pragma unroll
  for (int u = 0; u < 16; ++u){
    int dp = half * 16 + u;
    u32 v1 = po0[dp * 32 + q], v2 = po1[dp * 32 + q];
    float lo = (__builtin_bit_cast(float, v1 << 16)
              + __builtin_bit_cast(float, v2 << 16)) * linv;
    float hv = (__builtin_bit_cast(float, v1 & 0xffff0000u)
              + __builtin_bit_cast(float, v2 & 0xffff0000u)) * linv;
    u32 pw;
    asm("v_cvt_pk_bf16_f32 %0, %1, %2" : "=v"(pw) : "v"(lo), "v"(hv));
    *reinterpret_cast<u32*>(orow + 2 * dp) = pw;
  }
}

// ---------------- Output GEMM (R23 form): BM=128, BN=64, grid (64,9), gload_lds dbuf ----------------
__launch_bounds__(256)
__global__ void out_gemm_kernel(const bf16_t* __restrict__ A,
                                const bf16_t* __restrict__ Wob,
                                float* __restrict__ out)
{
  __shared__ bf16_t Ald[2][128 * 64];
  __shared__ bf16_t Bld[2][64 * 64];
  const int t = threadIdx.x, l = t & 63, w = t >> 6;
  const int wm = w >> 1, wn = w & 1;
  const int lane16 = l & 15, grp = l >> 4;
  const int m0 = blockIdx.x * 128;
  const int nt = blockIdx.y;
  const int nrow0 = nt * 64;

  const int sr = l >> 3;
  const int sc = ((l & 7) ^ sr) * 8;

  f32x4 acc[4][2];
  #pragma unroll
  for (int mi = 0; mi < 4; ++mi)
    #pragma unroll
    for (int ni = 0; ni < 2; ++ni)
      acc[mi][ni] = (f32x4){0.f, 0.f, 0.f, 0.f};

  auto STAGE = [&](int kt, int buf){
    const int k0 = kt * 64;
    #pragma unroll
    for (int u = 0; u < 4; ++u)
      gload16(A + (size_t)(m0 + w * 32 + u * 8 + sr) * Hdim + k0 + sc,
              &Ald[buf][(w * 32 + u * 8) * 64]);
    #pragma unroll
    for (int u = 0; u < 2; ++u)
      gload16(Wob + (size_t)(nrow0 + w * 16 + u * 8 + sr) * Hdim + k0 + sc,
              &Bld[buf][(w * 16 + u * 8) * 64]);
  };

  STAGE(0, 0);
  asm volatile("s_waitcnt vmcnt(0)" ::: "memory");
  __syncthreads();

  const int sl7 = lane16 & 7;
  for (int kt = 0; kt < 9; ++kt){
    const int buf = kt & 1;
    if (kt + 1 < 9) STAGE(kt + 1, buf ^ 1);
    #pragma unroll
    for (int ks = 0; ks < 2; ++ks){
      bf16x8 a[4], bb[2];
      #pragma unroll
      for (int mi = 0; mi < 4; ++mi){
        int row = wm * 64 + mi * 16 + lane16;
        a[mi] = *reinterpret_cast<const bf16x8*>(&Ald[buf][row * 64 + (((ks * 4 + grp) ^ sl7) * 8)]);
      }
      #pragma unroll
      for (int ni = 0; ni < 2; ++ni){
        int row = wn * 32 + ni * 16 + lane16;
        bb[ni] = *reinterpret_cast<const bf16x8*>(&Bld[buf][row * 64 + (((ks * 4 + grp) ^ sl7) * 8)]);
      }
      #pragma unroll
      for (int mi = 0; mi < 4; ++mi)
        #pragma unroll
        for (int ni = 0; ni < 2; ++ni)
          acc[mi][ni] = __builtin_amdgcn_mfma_f32_16x16x32_bf16(a[mi], bb[ni], acc[mi][ni], 0, 0, 0);
    }
    if (kt + 1 < 9){
      asm volatile("s_waitcnt vmcnt(0)" ::: "memory");
      __syncthreads();
    }
  }

  #pragma unroll
  for (int mi = 0; mi < 4; ++mi){
    #pragma unroll
    for (int ni = 0; ni < 2; ++ni){
      #pragma unroll
      for (int jj = 0; jj < 4; ++jj){
        int m = m0 + wm * 64 + mi * 16 + grp * 4 + jj;
        int n = nrow0 + wn * 32 + ni * 16 + lane16;
        out[(size_t)m * Hdim + n] = acc[mi][ni][jj];
      }
    }
  }
}

extern "C" void kernel_launch(void* const* d_in, const int* in_sizes, int n_in,
                              void* d_out, int out_size, void* d_ws, size_t ws_size,
                              hipStream_t stream) {
  const float* X   = (const float*)d_in[0];
  const int* pos   = (const int*)d_in[2];
  const float* Wq  = (const float*)d_in[3];
  const float* Wk  = (const float*)d_in[4];
  const float* Wv  = (const float*)d_in[5];
  const float* Wo  = (const float*)d_in[6];
  float* out = (float*)d_out;

  char* ws = (char*)d_ws;
  float* cost = (float*)ws;
  float* sint = (float*)(ws + 262144);
  bf16_t* qb  = (bf16_t*)(ws + 524288);
  bf16_t* kb  = qb + (size_t)Bsz * NH * Slen * HD;
  bf16_t* vt  = kb + (size_t)Bsz * NKV * Slen * HD;
  bf16_t* Xb  = vt + (size_t)Bsz * NKV * Slen * HD;
  bf16_t* ab  = Xb;                                  // alias: Xb dead after qkv_gemm
  bf16_t* Wb  = Xb + (size_t)8192 * 576;
  bf16_t* Wob = Wb + (size_t)960 * 576;
  u32*  part_O  = (u32*)(Wob + (size_t)576 * 576);   // 2304 slots x 2 waves x 4KB = 18.9MB
  float* part_l = (float*)(part_O + (size_t)2304 * 2 * 1024);  // 1.2MB

  const float QSCALE = 0.125f * 1.44269504088896f;

  setup_kernel<<<dim3(256 + 2736), dim3(256), 0, stream>>>(X, Wq, Wk, Wv, Wo, Xb, Wb, Wob, cost, sint);
  qkv_gemm_kernel<<<dim3(64, 8), dim3(256), 0, stream>>>(Xb, Wb, pos, cost, sint, QSCALE, qb, kb, vt);
  flash_attn_kernel<<<dim3(2304), dim3(128), 0, stream>>>(qb, kb, vt, part_O, part_l);
  combine_kernel<<<dim3(1152), dim3(128), 0, stream>>>(part_O, part_l, ab);
  out_gemm_kernel<<<dim3(64, 9), dim3(256), 0, stream>>>(ab, Wob, out);
}